// Round 2
// baseline (1591.382 us; speedup 1.0000x reference)
//
#include <hip/hip_runtime.h>
#include <hip/hip_bf16.h>
#include <stdint.h>

#define N_NODES 100000
#define DIM     64
#define NRELS   16
#define NBASE   8
#define HDIM    128
#define NEDGE   3200000
#define KDIM    1024   /* NRELS*DIM */

#define GRP     32                 /* nodes per group */
#define NGRP    (N_NODES / GRP)    /* 3125 */
#define NREP    8                  /* histogram contention replicas */
#define NK      (NGRP * NREP)      /* 25000 counters */

typedef __attribute__((ext_vector_type(8))) short  short8;
typedef __attribute__((ext_vector_type(4))) float  f32x4;

/* ---- ws layout ---- */
#define OFF_VEFF 0u
#define OFF_CNT  262144u                       /* NK ints = 100000 B */
#define OFF_OFS  364544u                       /* NK+1 ints          */
#define OFF_CUR  464640u                       /* NK ints            */
#define OFF_REC  564736u                       /* E * 8 B            */
#define WS_NEED  (564736u + (size_t)NEDGE * 8u)

static __device__ __forceinline__ unsigned short f2bf(float x) {
    union { float f; unsigned u; } t; t.f = x;
    unsigned u = t.u;
    unsigned r = u + 0x7FFFu + ((u >> 16) & 1u);   /* RNE */
    return (unsigned short)(r >> 16);
}
static __device__ __forceinline__ unsigned pack2bf16(float a, float b) {
    return (unsigned)f2bf(a) | ((unsigned)f2bf(b) << 16);
}

/* sup fp32 [32][1024] swizzled, 16B-granule XOR */
#define SW32(row, cb) ((row) * 4096 + ((cb) ^ (((row) & 7) << 4)))
/* abuf bf16 [32][1024] swizzled (overlaps sup low 64KB) */
#define SWA(row, cb)  ((row) * 2048 + ((cb) ^ (((row) & 7) << 4)))

/* ---- kernel 1: Veff in MFMA B-fragment layout (verified round 1) ---- */
__global__ __launch_bounds__(256) void build_veff_frag(
        const float* __restrict__ W, const float* __restrict__ Wc,
        __hip_bfloat16* __restrict__ veff) {
    int idx = blockIdx.x * 256 + threadIdx.x;
    int c = idx >> 7;
    int h = idx & 127;
    int r_ = c & 15;
    int d_ = c >> 4;
    float acc = 0.f;
#pragma unroll
    for (int b = 0; b < NBASE; ++b)
        acc += Wc[r_ * NBASE + b] * W[(b * DIM + d_) * HDIM + h];
    int kt = c >> 5, ko = c & 31;
    int lane = ((ko >> 3) << 4) | (h & 15);
    int j = ko & 7;
    int hb = h >> 4;
    ((unsigned short*)veff)[(size_t)((kt * 8 + hb) * 64 + lane) * 8 + j] = f2bf(acc);
}

/* ---- kernel 2: histogram (replicated counters) ---- */
__global__ __launch_bounds__(256) void hist_kernel(
        const int* __restrict__ edst, int* __restrict__ cnt8) {
    int e = blockIdx.x * 256 + threadIdx.x;          /* grid = E/256 exact */
    int g = edst[e] >> 5;
    atomicAdd(&cnt8[(g << 3) | (blockIdx.x & 7)], 1);
}

/* ---- kernel 3: exclusive scan of 25000 counters (1 block, 256 thr) ---- */
__global__ __launch_bounds__(256) void scan_kernel(
        const int* __restrict__ cnt8, int* __restrict__ ofs8, int* __restrict__ cur8) {
    int t = threadIdx.x;
    int lane = t & 63, w = t >> 6;
    const int CH = 98;
    int b0 = t * CH, b1 = b0 + CH; if (b1 > NK) b1 = NK; if (b0 > NK) b0 = NK;
    int s = 0;
    for (int i = b0; i < b1; ++i) s += cnt8[i];
    int x = s;
#pragma unroll
    for (int d = 1; d < 64; d <<= 1) { int y = __shfl_up(x, d); if (lane >= d) x += y; }
    __shared__ int wsum[4];
    if (lane == 63) wsum[w] = x;
    __syncthreads();
    int wadd = 0;
    for (int i = 0; i < 4; ++i) if (i < w) wadd += wsum[i];
    int run = wadd + x - s;        /* exclusive prefix */
    for (int i = b0; i < b1; ++i) {
        ofs8[i] = run; cur8[i] = run; run += cnt8[i];
    }
    if (t == 255) ofs8[NK] = run;  /* = E */
}

/* ---- kernel 4: scatter edges into bins ---- */
__global__ __launch_bounds__(256) void scatter_bin(
        const int* __restrict__ esrc, const int* __restrict__ edst,
        const int* __restrict__ erel, const float* __restrict__ eval,
        int* __restrict__ cur8, uint2* __restrict__ recs) {
    int e = blockIdx.x * 256 + threadIdx.x;          /* grid = E/256 exact */
    int dst = edst[e];
    int g = dst >> 5;
    int pos = atomicAdd(&cur8[(g << 3) | (blockIdx.x & 7)], 1);
    unsigned rx = (unsigned)esrc[e] | ((unsigned)erel[e] << 17)
                | ((unsigned)(dst & 31) << 21);
    uint2 r; r.x = rx; r.y = __float_as_uint(eval[e]);
    recs[pos] = r;
}

/* ---- kernel 5: fused aggregate (LDS fp32 atomics) + convert + MFMA GEMM ---- */
__global__ __launch_bounds__(512, 1) void fused_agg_gemm(
        const float* __restrict__ vertex, const uint2* __restrict__ recs,
        const int* __restrict__ ofs8, const __hip_bfloat16* __restrict__ veff,
        const float* __restrict__ bias, float* __restrict__ out) {
    __shared__ __align__(16) unsigned char smem[131072];   /* 128 KiB */
    int t = threadIdx.x;
    int g = blockIdx.x;

    /* zero sup */
    for (int i = t; i < 131072 / 16; i += 512)
        ((uint4*)smem)[i] = make_uint4(0, 0, 0, 0);
    __syncthreads();

    int start = ofs8[g * 8];
    int cnt   = ofs8[g * 8 + 8] - start;

    /* ---- edge accumulation: 32 slices x 16 lanes ---- */
    int slice = t >> 4, p = t & 15;
#define EDGE_BODY(r)                                                        \
    {                                                                       \
        unsigned rx = (unsigned)__shfl((int)myrec.x, (r), 16);              \
        unsigned ry = (unsigned)__shfl((int)myrec.y, (r), 16);              \
        int src = rx & 0x1FFFF;                                             \
        int rel = (rx >> 17) & 15;                                          \
        int ln  = (rx >> 21) & 31;                                          \
        float val = __uint_as_float(ry);                                    \
        float4 v = ((const float4*)vertex)[(size_t)src * 16 + p];           \
        float* sp = (float*)(smem + SW32(ln, (rel * 64 + p * 4) * 4));      \
        unsafeAtomicAdd(sp + 0, v.x * val);                                 \
        unsafeAtomicAdd(sp + 1, v.y * val);                                 \
        unsafeAtomicAdd(sp + 2, v.z * val);                                 \
        unsafeAtomicAdd(sp + 3, v.w * val);                                 \
    }
    for (int base = slice * 16; base < cnt; base += 512) {
        int rem = cnt - base; if (rem > 16) rem = 16;
        uint2 myrec = (p < rem) ? recs[start + base + p] : make_uint2(0u, 0u);
        if (rem == 16) {
#pragma unroll 4
            for (int r = 0; r < 16; ++r) EDGE_BODY(r)
        } else {
            for (int r = 0; r < rem; ++r) EDGE_BODY(r)
        }
    }
#undef EDGE_BODY
    __syncthreads();

    /* ---- convert sup fp32 -> abuf bf16 (in place, chunked, hazard-free) ---- */
    for (int c = 0; c < 4; ++c) {
        int row  = c * 8 + (t >> 6);
        int colf = (t & 63) * 16;
        f32x4 q0 = *(const f32x4*)(smem + SW32(row, (colf +  0) * 4));
        f32x4 q1 = *(const f32x4*)(smem + SW32(row, (colf +  4) * 4));
        f32x4 q2 = *(const f32x4*)(smem + SW32(row, (colf +  8) * 4));
        f32x4 q3 = *(const f32x4*)(smem + SW32(row, (colf + 12) * 4));
        __syncthreads();
        uint4 w0, w1;
        w0.x = pack2bf16(q0[0], q0[1]); w0.y = pack2bf16(q0[2], q0[3]);
        w0.z = pack2bf16(q1[0], q1[1]); w0.w = pack2bf16(q1[2], q1[3]);
        w1.x = pack2bf16(q2[0], q2[1]); w1.y = pack2bf16(q2[2], q2[3]);
        w1.z = pack2bf16(q3[0], q3[1]); w1.w = pack2bf16(q3[2], q3[3]);
        *(uint4*)(smem + SWA(row, colf * 2 +  0)) = w0;
        *(uint4*)(smem + SWA(row, colf * 2 + 16)) = w1;
        __syncthreads();
    }

    /* ---- GEMM: [32 x 1024] @ veff[1024 x 128]; wave w owns h-block w ---- */
    int lane = t & 63, w = t >> 6;
    int l15 = lane & 15, lhi = lane >> 4;
    f32x4 acc0 = (f32x4)0.f, acc1 = (f32x4)0.f;
#pragma unroll
    for (int kt = 0; kt < 32; ++kt) {
        short8 b  = ((const short8*)veff)[(size_t)(kt * 8 + w) * 64 + lane];
        short8 a0 = *(const short8*)(smem + SWA(l15,      kt * 64 + lhi * 16));
        short8 a1 = *(const short8*)(smem + SWA(16 + l15, kt * 64 + lhi * 16));
        acc0 = __builtin_amdgcn_mfma_f32_16x16x32_bf16(a0, b, acc0, 0, 0, 0);
        acc1 = __builtin_amdgcn_mfma_f32_16x16x32_bf16(a1, b, acc1, 0, 0, 0);
    }
    int h = w * 16 + l15;
    float bv = bias[h];
#pragma unroll
    for (int j = 0; j < 4; ++j) {
        out[(size_t)(g * 32 + lhi * 4 + j) * HDIM + h]      = acc0[j] + bv;
        out[(size_t)(g * 32 + 16 + lhi * 4 + j) * HDIM + h] = acc1[j] + bv;
    }
}

/* ---------- slow fallback (only if ws too small) ---------- */
__global__ __launch_bounds__(256) void build_veff_plain(
        const float* __restrict__ W, const float* __restrict__ Wc,
        float* __restrict__ veff) {
    int idx = blockIdx.x * 256 + threadIdx.x;
    int c = idx >> 7, h = idx & 127;
    float acc = 0.f;
#pragma unroll
    for (int b = 0; b < NBASE; ++b)
        acc += Wc[(c & 15) * NBASE + b] * W[(b * DIM + (c >> 4)) * HDIM + h];
    veff[c * HDIM + h] = acc;
}
__global__ __launch_bounds__(256) void init_out_bias(
        const float* __restrict__ bias, float* __restrict__ out) {
    int idx = blockIdx.x * 256 + threadIdx.x;
    if (idx < N_NODES * HDIM) out[idx] = bias[idx & 127];
}
__global__ __launch_bounds__(128) void edge_slow(
        const float* __restrict__ vertex, const float* __restrict__ eval,
        const int* __restrict__ esrc, const int* __restrict__ edst,
        const int* __restrict__ erel, const float* __restrict__ veff,
        float* __restrict__ out) {
    int e = blockIdx.x;
    int h = threadIdx.x;
    __shared__ float vrow[DIM];
    int src = esrc[e], dst = edst[e], rel = erel[e];
    float val = eval[e];
    if (h < DIM) vrow[h] = vertex[(size_t)src * DIM + h];
    __syncthreads();
    float acc = 0.f;
#pragma unroll 8
    for (int d = 0; d < DIM; ++d)
        acc += vrow[d] * veff[(rel * DIM + d) * HDIM + h];
    atomicAdd(out + (size_t)dst * HDIM + h, val * acc);
}

extern "C" void kernel_launch(void* const* d_in, const int* in_sizes, int n_in,
                              void* d_out, int out_size, void* d_ws, size_t ws_size,
                              hipStream_t stream) {
    const float* vertex   = (const float*)d_in[0];
    const float* edge_val = (const float*)d_in[1];
    const float* W        = (const float*)d_in[2];
    const float* W_comp   = (const float*)d_in[3];
    const float* B        = (const float*)d_in[4];
    const int*   edge_src = (const int*)d_in[5];
    const int*   edge_dst = (const int*)d_in[6];
    const int*   edge_rel = (const int*)d_in[7];
    float* out = (float*)d_out;

    if (ws_size >= WS_NEED) {
        __hip_bfloat16* veff = (__hip_bfloat16*)((char*)d_ws + OFF_VEFF);
        int*   cnt8 = (int*)((char*)d_ws + OFF_CNT);
        int*   ofs8 = (int*)((char*)d_ws + OFF_OFS);
        int*   cur8 = (int*)((char*)d_ws + OFF_CUR);
        uint2* recs = (uint2*)((char*)d_ws + OFF_REC);

        hipMemsetAsync(cnt8, 0, NK * sizeof(int), stream);
        build_veff_frag<<<KDIM * HDIM / 256, 256, 0, stream>>>(W, W_comp, veff);
        hist_kernel<<<NEDGE / 256, 256, 0, stream>>>(edge_dst, cnt8);
        scan_kernel<<<1, 256, 0, stream>>>(cnt8, ofs8, cur8);
        scatter_bin<<<NEDGE / 256, 256, 0, stream>>>(
            edge_src, edge_dst, edge_rel, edge_val, cur8, recs);
        fused_agg_gemm<<<NGRP, 512, 0, stream>>>(vertex, recs, ofs8, veff, B, out);
    } else {
        float* veff = (float*)d_ws;
        build_veff_plain<<<KDIM * HDIM / 256, 256, 0, stream>>>(W, W_comp, veff);
        init_out_bias<<<(N_NODES * HDIM + 255) / 256, 256, 0, stream>>>(B, out);
        edge_slow<<<NEDGE, 128, 0, stream>>>(
            vertex, edge_val, edge_src, edge_dst, edge_rel, veff, out);
    }
}

// Round 3
// 922.790 us; speedup vs baseline: 1.7245x; 1.7245x over previous
//
#include <hip/hip_runtime.h>
#include <hip/hip_bf16.h>
#include <stdint.h>

#define N_NODES 100000
#define DIM     64
#define NRELS   16
#define NBASE   8
#define HDIM    128
#define NEDGE   3200000
#define KDIM    1024               /* NRELS*DIM */
#define NSEG    (N_NODES * NRELS)  /* 1,600,000 */
#define NBLKA   ((NSEG + 1023) / 1024)   /* 1563 */

typedef __attribute__((ext_vector_type(8))) short  short8;
typedef __attribute__((ext_vector_type(4))) float  f32x4;

/* ---- ws layout (bytes) ---- */
#define OFF_VEFF  0u
#define OFF_CNT   262144u                       /* NSEG ints            */
#define OFF_OFS   6662144u                      /* NSEG+1 ints (+pad)   */
#define OFF_CUR   13062160u                     /* NSEG ints            */
#define OFF_BSUM  19462160u                     /* NBLKA ints (+pad)    */
#define OFF_BSC   19468416u                     /* NBLKA ints (+pad)    */
#define OFF_REC   19474672u                     /* E * 8 B              */
#define WS_NEED   (OFF_REC + (size_t)NEDGE * 8u)

static __device__ __forceinline__ unsigned short f2bf(float x) {
    union { float f; unsigned u; } t; t.f = x;
    unsigned u = t.u;
    unsigned r = u + 0x7FFFu + ((u >> 16) & 1u);   /* RNE */
    return (unsigned short)(r >> 16);
}

/* ---- kernel 1: Veff in MFMA B-fragment layout (verified r1/r2) ---- */
__global__ __launch_bounds__(256) void build_veff_frag(
        const float* __restrict__ W, const float* __restrict__ Wc,
        __hip_bfloat16* __restrict__ veff) {
    int idx = blockIdx.x * 256 + threadIdx.x;
    int c = idx >> 7;
    int h = idx & 127;
    float acc = 0.f;
#pragma unroll
    for (int b = 0; b < NBASE; ++b)
        acc += Wc[(c & 15) * NBASE + b] * W[(b * DIM + (c >> 4)) * HDIM + h];
    int kt = c >> 5, ko = c & 31;
    int lane = ((ko >> 3) << 4) | (h & 15);
    int j = ko & 7;
    int hb = h >> 4;
    ((unsigned short*)veff)[(size_t)((kt * 8 + hb) * 64 + lane) * 8 + j] = f2bf(acc);
}

/* ---- kernel 2: histogram over (dst*16+rel) ---- */
__global__ __launch_bounds__(256) void hist_kernel(
        const int* __restrict__ edst, const int* __restrict__ erel,
        int* __restrict__ cnt) {
    int e = blockIdx.x * 256 + threadIdx.x;          /* grid exact */
    atomicAdd(&cnt[edst[e] * NRELS + erel[e]], 1);
}

/* ---- kernel 3a: per-1024-chunk sums ---- */
__global__ __launch_bounds__(256) void scanA(
        const int* __restrict__ cnt, int* __restrict__ bsum) {
    __shared__ int bs;
    int b = blockIdx.x, t = threadIdx.x;
    if (t == 0) bs = 0;
    __syncthreads();
    int base = b * 1024 + t * 4;
    int s = 0;
#pragma unroll
    for (int k = 0; k < 4; ++k)
        if (base + k < NSEG) s += cnt[base + k];
    atomicAdd(&bs, s);
    __syncthreads();
    if (t == 0) bsum[b] = bs;
}

/* ---- kernel 3b: exclusive scan of NBLKA chunk sums (1 block) ---- */
__global__ __launch_bounds__(256) void scanB(
        const int* __restrict__ bsum, int* __restrict__ bscan) {
    int t = threadIdx.x;
    int lane = t & 63, w = t >> 6;
    const int CH = 7;                                  /* 7*256 >= 1563 */
    int b0 = t * CH, b1 = b0 + CH;
    if (b1 > NBLKA) b1 = NBLKA;
    if (b0 > NBLKA) b0 = NBLKA;
    int s = 0;
    for (int i = b0; i < b1; ++i) s += bsum[i];
    int x = s;
#pragma unroll
    for (int d = 1; d < 64; d <<= 1) { int y = __shfl_up(x, d); if (lane >= d) x += y; }
    __shared__ int wsum[4];
    if (lane == 63) wsum[w] = x;
    __syncthreads();
    int wadd = 0;
    for (int i = 0; i < 4; ++i) if (i < w) wadd += wsum[i];
    int run = wadd + x - s;
    for (int i = b0; i < b1; ++i) { bscan[i] = run; run += bsum[i]; }
}

/* ---- kernel 3c: local scan + chunk base -> ofs, cur ---- */
__global__ __launch_bounds__(256) void scanC(
        const int* __restrict__ cnt, const int* __restrict__ bscan,
        int* __restrict__ ofs, int* __restrict__ cur) {
    int b = blockIdx.x, t = threadIdx.x;
    int lane = t & 63, w = t >> 6;
    int base = b * 1024 + t * 4;
    int c[4]; int s = 0;
#pragma unroll
    for (int k = 0; k < 4; ++k) {
        c[k] = (base + k < NSEG) ? cnt[base + k] : 0;
        s += c[k];
    }
    int x = s;
#pragma unroll
    for (int d = 1; d < 64; d <<= 1) { int y = __shfl_up(x, d); if (lane >= d) x += y; }
    __shared__ int wsum[4];
    if (lane == 63) wsum[w] = x;
    __syncthreads();
    int wadd = 0;
    for (int i = 0; i < 4; ++i) if (i < w) wadd += wsum[i];
    int run = bscan[b] + wadd + x - s;                  /* exclusive */
#pragma unroll
    for (int k = 0; k < 4; ++k) {
        if (base + k < NSEG) {
            ofs[base + k] = run;
            cur[base + k] = run;
            run += c[k];
            if (base + k == NSEG - 1) ofs[NSEG] = run;  /* = E */
        }
    }
}

/* ---- kernel 4: scatter records into segment bins ---- */
__global__ __launch_bounds__(256) void scatter_bin(
        const int* __restrict__ esrc, const int* __restrict__ edst,
        const int* __restrict__ erel, const float* __restrict__ eval,
        int* __restrict__ cur, uint2* __restrict__ recs) {
    int e = blockIdx.x * 256 + threadIdx.x;            /* grid exact */
    int rel = erel[e];
    int key = edst[e] * NRELS + rel;
    int pos = atomicAdd(&cur[key], 1);
    uint2 r;
    r.x = (unsigned)esrc[e] | ((unsigned)rel << 17);
    r.y = __float_as_uint(eval[e]);
    recs[pos] = r;
}

/* ---- kernel 5: fused register-accumulate + MFMA GEMM ----
   512 thr / 8 waves / 32 nodes / 64 KiB LDS -> 2 blocks per CU.
   Wave w owns nodes w*4..w*4+3. Edges of a node are contiguous and
   rel-sorted: one fp32 acc per lane, flushed to bf16 LDS on rel change. */
__global__ __launch_bounds__(512, 4) void fused_agg_gemm(
        const float* __restrict__ vertex, const uint2* __restrict__ recs,
        const int* __restrict__ ofs, const __hip_bfloat16* __restrict__ veff,
        const float* __restrict__ bias, float* __restrict__ out) {
    __shared__ __align__(16) unsigned char smem[65536];   /* A: [32][1024] bf16, XOR-swz */
    int t = threadIdx.x;
    int g = blockIdx.x;
    int w = t >> 6, lane = t & 63;

    /* zero A (empty segments must read 0) */
    for (int i = t; i < 4096; i += 512)
        ((uint4*)smem)[i] = make_uint4(0, 0, 0, 0);
    __syncthreads();

    /* ---- aggregation ---- */
#pragma unroll
    for (int i = 0; i < 4; ++i) {
        int nloc = w * 4 + i;
        int n = g * 32 + nloc;
        unsigned swz = (unsigned)((nloc & 7) << 4);
        unsigned rowb = (unsigned)nloc * 2048 + (unsigned)lane * 2;
        int e    = ofs[n * 16];
        int eEnd = ofs[n * 16 + 16];
        float acc = 0.f;
        int currel = -1;
#pragma unroll 4
        for (; e < eEnd; ++e) {
            uint2 rec = recs[e];
            int rel = __builtin_amdgcn_readfirstlane((int)(rec.x >> 17) & 15);
            if (rel != currel) {
                if (currel >= 0)
                    *(unsigned short*)(smem + ((rowb + (unsigned)currel * 128) ^ swz)) = f2bf(acc);
                acc = 0.f;
                currel = rel;
            }
            float v = vertex[(size_t)(rec.x & 0x1FFFFu) * DIM + lane];
            acc = fmaf(__uint_as_float(rec.y), v, acc);
        }
        if (currel >= 0)
            *(unsigned short*)(smem + ((rowb + (unsigned)currel * 128) ^ swz)) = f2bf(acc);
    }
    __syncthreads();

    /* ---- GEMM: [32 x 1024] @ veff[1024 x 128]; wave w owns h-block w ---- */
    int l15 = lane & 15, lhi = lane >> 4;
    unsigned axor = (unsigned)((l15 & 7) << 4);
    f32x4 acc0 = (f32x4)0.f, acc1 = (f32x4)0.f;
#pragma unroll
    for (int kt = 0; kt < 32; ++kt) {
        short8 b  = ((const short8*)veff)[(size_t)(kt * 8 + w) * 64 + lane];
        unsigned cb = (unsigned)(kt * 64 + lhi * 16);
        short8 a0 = *(const short8*)(smem + (((unsigned)l15 * 2048 + cb) ^ axor));
        short8 a1 = *(const short8*)(smem + (((unsigned)(16 + l15) * 2048 + cb) ^ axor));
        acc0 = __builtin_amdgcn_mfma_f32_16x16x32_bf16(a0, b, acc0, 0, 0, 0);
        acc1 = __builtin_amdgcn_mfma_f32_16x16x32_bf16(a1, b, acc1, 0, 0, 0);
    }
    int h = w * 16 + l15;
    float bv = bias[h];
#pragma unroll
    for (int j = 0; j < 4; ++j) {
        out[(size_t)(g * 32 + lhi * 4 + j) * HDIM + h]      = acc0[j] + bv;
        out[(size_t)(g * 32 + 16 + lhi * 4 + j) * HDIM + h] = acc1[j] + bv;
    }
}

/* ---------- slow fallback (only if ws too small) ---------- */
__global__ __launch_bounds__(256) void build_veff_plain(
        const float* __restrict__ W, const float* __restrict__ Wc,
        float* __restrict__ veff) {
    int idx = blockIdx.x * 256 + threadIdx.x;
    int c = idx >> 7, h = idx & 127;
    float acc = 0.f;
#pragma unroll
    for (int b = 0; b < NBASE; ++b)
        acc += Wc[(c & 15) * NBASE + b] * W[(b * DIM + (c >> 4)) * HDIM + h];
    veff[c * HDIM + h] = acc;
}
__global__ __launch_bounds__(256) void init_out_bias(
        const float* __restrict__ bias, float* __restrict__ out) {
    int idx = blockIdx.x * 256 + threadIdx.x;
    if (idx < N_NODES * HDIM) out[idx] = bias[idx & 127];
}
__global__ __launch_bounds__(128) void edge_slow(
        const float* __restrict__ vertex, const float* __restrict__ eval,
        const int* __restrict__ esrc, const int* __restrict__ edst,
        const int* __restrict__ erel, const float* __restrict__ veff,
        float* __restrict__ out) {
    int e = blockIdx.x;
    int h = threadIdx.x;
    __shared__ float vrow[DIM];
    int src = esrc[e], dst = edst[e], rel = erel[e];
    float val = eval[e];
    if (h < DIM) vrow[h] = vertex[(size_t)src * DIM + h];
    __syncthreads();
    float acc = 0.f;
#pragma unroll 8
    for (int d = 0; d < DIM; ++d)
        acc += vrow[d] * veff[(rel * DIM + d) * HDIM + h];
    atomicAdd(out + (size_t)dst * HDIM + h, val * acc);
}

extern "C" void kernel_launch(void* const* d_in, const int* in_sizes, int n_in,
                              void* d_out, int out_size, void* d_ws, size_t ws_size,
                              hipStream_t stream) {
    const float* vertex   = (const float*)d_in[0];
    const float* edge_val = (const float*)d_in[1];
    const float* W        = (const float*)d_in[2];
    const float* W_comp   = (const float*)d_in[3];
    const float* B        = (const float*)d_in[4];
    const int*   edge_src = (const int*)d_in[5];
    const int*   edge_dst = (const int*)d_in[6];
    const int*   edge_rel = (const int*)d_in[7];
    float* out = (float*)d_out;

    if (ws_size >= WS_NEED) {
        __hip_bfloat16* veff = (__hip_bfloat16*)((char*)d_ws + OFF_VEFF);
        int*   cnt   = (int*)((char*)d_ws + OFF_CNT);
        int*   ofs   = (int*)((char*)d_ws + OFF_OFS);
        int*   cur   = (int*)((char*)d_ws + OFF_CUR);
        int*   bsum  = (int*)((char*)d_ws + OFF_BSUM);
        int*   bscan = (int*)((char*)d_ws + OFF_BSC);
        uint2* recs  = (uint2*)((char*)d_ws + OFF_REC);

        hipMemsetAsync(cnt, 0, NSEG * sizeof(int), stream);
        build_veff_frag<<<KDIM * HDIM / 256, 256, 0, stream>>>(W, W_comp, veff);
        hist_kernel<<<NEDGE / 256, 256, 0, stream>>>(edge_dst, edge_rel, cnt);
        scanA<<<NBLKA, 256, 0, stream>>>(cnt, bsum);
        scanB<<<1, 256, 0, stream>>>(bsum, bscan);
        scanC<<<NBLKA, 256, 0, stream>>>(cnt, bscan, ofs, cur);
        scatter_bin<<<NEDGE / 256, 256, 0, stream>>>(
            edge_src, edge_dst, edge_rel, edge_val, cur, recs);
        fused_agg_gemm<<<N_NODES / 32, 512, 0, stream>>>(vertex, recs, ofs, veff, B, out);
    } else {
        float* veff = (float*)d_ws;
        build_veff_plain<<<KDIM * HDIM / 256, 256, 0, stream>>>(W, W_comp, veff);
        init_out_bias<<<(N_NODES * HDIM + 255) / 256, 256, 0, stream>>>(B, out);
        edge_slow<<<NEDGE, 128, 0, stream>>>(
            vertex, edge_val, edge_src, edge_dst, edge_rel, veff, out);
    }
}

// Round 4
// 520.575 us; speedup vs baseline: 3.0570x; 1.7726x over previous
//
#include <hip/hip_runtime.h>
#include <hip/hip_bf16.h>
#include <stdint.h>

#define N_NODES 100000
#define DIM     64
#define NRELS   16
#define NBASE   8
#define HDIM    128
#define NEDGE   3200000
#define KDIM    1024               /* NRELS*DIM */
#define NSEG    (N_NODES * NRELS)  /* 1,600,000 */
#define NBLKA   ((NSEG + 1023) / 1024)   /* 1563 */
#define REC_PAD 256

typedef __attribute__((ext_vector_type(8))) short  short8;
typedef __attribute__((ext_vector_type(4))) float  f32x4;

/* ---- ws layout (bytes) ---- */
#define OFF_VEFF  0u
#define OFF_CNT   262144u                       /* NSEG ints            */
#define OFF_OFS   6662144u                      /* NSEG+1 ints (+pad)   */
#define OFF_CUR   13062160u                     /* NSEG ints            */
#define OFF_BSUM  19462160u                     /* NBLKA ints (+pad)    */
#define OFF_BSC   19468416u                     /* NBLKA ints (+pad)    */
#define OFF_REC   19474672u                     /* (E+pad) * 8 B        */
#define WS_NEED   (OFF_REC + (size_t)(NEDGE + REC_PAD) * 8u)

static __device__ __forceinline__ unsigned short f2bf(float x) {
    union { float f; unsigned u; } t; t.f = x;
    unsigned u = t.u;
    unsigned r = u + 0x7FFFu + ((u >> 16) & 1u);   /* RNE */
    return (unsigned short)(r >> 16);
}

/* ---- kernel 1: Veff in MFMA B-fragment layout (verified r1-r3) ---- */
__global__ __launch_bounds__(256) void build_veff_frag(
        const float* __restrict__ W, const float* __restrict__ Wc,
        __hip_bfloat16* __restrict__ veff) {
    int idx = blockIdx.x * 256 + threadIdx.x;
    int c = idx >> 7;
    int h = idx & 127;
    float acc = 0.f;
#pragma unroll
    for (int b = 0; b < NBASE; ++b)
        acc += Wc[(c & 15) * NBASE + b] * W[(b * DIM + (c >> 4)) * HDIM + h];
    int kt = c >> 5, ko = c & 31;
    int lane = ((ko >> 3) << 4) | (h & 15);
    int j = ko & 7;
    int hb = h >> 4;
    ((unsigned short*)veff)[(size_t)((kt * 8 + hb) * 64 + lane) * 8 + j] = f2bf(acc);
}

/* ---- kernel 2: histogram over (dst*16+rel) ---- */
__global__ __launch_bounds__(256) void hist_kernel(
        const int* __restrict__ edst, const int* __restrict__ erel,
        int* __restrict__ cnt) {
    int e = blockIdx.x * 256 + threadIdx.x;          /* grid exact */
    atomicAdd(&cnt[edst[e] * NRELS + erel[e]], 1);
}

/* ---- kernel 3a: per-1024-chunk sums ---- */
__global__ __launch_bounds__(256) void scanA(
        const int* __restrict__ cnt, int* __restrict__ bsum) {
    __shared__ int bs;
    int b = blockIdx.x, t = threadIdx.x;
    if (t == 0) bs = 0;
    __syncthreads();
    int base = b * 1024 + t * 4;
    int s = 0;
#pragma unroll
    for (int k = 0; k < 4; ++k)
        if (base + k < NSEG) s += cnt[base + k];
    atomicAdd(&bs, s);
    __syncthreads();
    if (t == 0) bsum[b] = bs;
}

/* ---- kernel 3b: exclusive scan of NBLKA chunk sums (1 block) ---- */
__global__ __launch_bounds__(256) void scanB(
        const int* __restrict__ bsum, int* __restrict__ bscan) {
    int t = threadIdx.x;
    int lane = t & 63, w = t >> 6;
    const int CH = 7;
    int b0 = t * CH, b1 = b0 + CH;
    if (b1 > NBLKA) b1 = NBLKA;
    if (b0 > NBLKA) b0 = NBLKA;
    int s = 0;
    for (int i = b0; i < b1; ++i) s += bsum[i];
    int x = s;
#pragma unroll
    for (int d = 1; d < 64; d <<= 1) { int y = __shfl_up(x, d); if (lane >= d) x += y; }
    __shared__ int wsum[4];
    if (lane == 63) wsum[w] = x;
    __syncthreads();
    int wadd = 0;
    for (int i = 0; i < 4; ++i) if (i < w) wadd += wsum[i];
    int run = wadd + x - s;
    for (int i = b0; i < b1; ++i) { bscan[i] = run; run += bsum[i]; }
}

/* ---- kernel 3c: local scan + chunk base -> ofs, cur ---- */
__global__ __launch_bounds__(256) void scanC(
        const int* __restrict__ cnt, const int* __restrict__ bscan,
        int* __restrict__ ofs, int* __restrict__ cur) {
    int b = blockIdx.x, t = threadIdx.x;
    int lane = t & 63, w = t >> 6;
    int base = b * 1024 + t * 4;
    int c[4]; int s = 0;
#pragma unroll
    for (int k = 0; k < 4; ++k) {
        c[k] = (base + k < NSEG) ? cnt[base + k] : 0;
        s += c[k];
    }
    int x = s;
#pragma unroll
    for (int d = 1; d < 64; d <<= 1) { int y = __shfl_up(x, d); if (lane >= d) x += y; }
    __shared__ int wsum[4];
    if (lane == 63) wsum[w] = x;
    __syncthreads();
    int wadd = 0;
    for (int i = 0; i < 4; ++i) if (i < w) wadd += wsum[i];
    int run = bscan[b] + wadd + x - s;
#pragma unroll
    for (int k = 0; k < 4; ++k) {
        if (base + k < NSEG) {
            ofs[base + k] = run;
            cur[base + k] = run;
            run += c[k];
            if (base + k == NSEG - 1) ofs[NSEG] = run;  /* = E */
        }
    }
}

/* ---- kernel 4: scatter records into segment bins ---- */
__global__ __launch_bounds__(256) void scatter_bin(
        const int* __restrict__ esrc, const int* __restrict__ edst,
        const int* __restrict__ erel, const float* __restrict__ eval,
        int* __restrict__ cur, uint2* __restrict__ recs) {
    int e = blockIdx.x * 256 + threadIdx.x;            /* grid exact */
    int rel = erel[e];
    int key = edst[e] * NRELS + rel;
    int pos = atomicAdd(&cur[key], 1);
    uint2 r;
    r.x = (unsigned)esrc[e] | ((unsigned)rel << 17);
    r.y = __float_as_uint(eval[e]);
    recs[pos] = r;
}

/* ---- kernel 5: fused branchless aggregate + MFMA GEMM ----
   512 thr / 8 waves / 32 nodes. Quarter-wave (16 lanes x float4) per node.
   Edges (node,rel)-sorted: acc in registers, reset-on-rel-change via cndmask,
   store-every-edge (overwrite; last write of a rel-run = full sum).
   8-edge chunks, rec double-buffer, all loads batched (no branches in body). */
__global__ __launch_bounds__(512, 4) void fused_agg_gemm(
        const float* __restrict__ vertex, const uint2* __restrict__ recs,
        const int* __restrict__ ofs, const __hip_bfloat16* __restrict__ veff,
        const float* __restrict__ bias, float* __restrict__ out) {
    __shared__ __align__(16) unsigned char smem[33 * 2048];   /* 32 A-rows + scratch row */
    int t = threadIdx.x;
    int g = blockIdx.x;
    int w = t >> 6, lane = t & 63;
    int q = lane >> 4, p = lane & 15;
    int nloc = w * 4 + q;
    int n = g * 32 + nloc;

    for (int i = t; i < 33 * 2048 / 16; i += 512)
        ((uint4*)smem)[i] = make_uint4(0, 0, 0, 0);
    __syncthreads();

    int e0 = ofs[n * 16];
    int e1 = ofs[n * 16 + 16];

    f32x4 acc = (f32x4)0.f;
    int currel = -1;
    const float4* vtx4 = (const float4*)vertex;

    uint2 r0, r1, r2, r3, r4, r5, r6, r7;
    r0 = recs[e0 + 0]; r1 = recs[e0 + 1]; r2 = recs[e0 + 2]; r3 = recs[e0 + 3];
    r4 = recs[e0 + 4]; r5 = recs[e0 + 5]; r6 = recs[e0 + 6]; r7 = recs[e0 + 7];

    for (int base = e0; __any(base < e1); base += 8) {
        /* vertex gathers for current chunk (issue all 8) */
        float4 v0 = vtx4[(size_t)(r0.x & 0x1FFFFu) * 16 + p];
        float4 v1 = vtx4[(size_t)(r1.x & 0x1FFFFu) * 16 + p];
        float4 v2 = vtx4[(size_t)(r2.x & 0x1FFFFu) * 16 + p];
        float4 v3 = vtx4[(size_t)(r3.x & 0x1FFFFu) * 16 + p];
        float4 v4 = vtx4[(size_t)(r4.x & 0x1FFFFu) * 16 + p];
        float4 v5 = vtx4[(size_t)(r5.x & 0x1FFFFu) * 16 + p];
        float4 v6 = vtx4[(size_t)(r6.x & 0x1FFFFu) * 16 + p];
        float4 v7 = vtx4[(size_t)(r7.x & 0x1FFFFu) * 16 + p];
        /* prefetch next chunk's records */
        int nb = base + 8;
        uint2 n0 = recs[nb + 0], n1 = recs[nb + 1], n2 = recs[nb + 2], n3 = recs[nb + 3];
        uint2 n4 = recs[nb + 4], n5 = recs[nb + 5], n6 = recs[nb + 6], n7 = recs[nb + 7];

#define PROC(K, RK, VK)                                                       \
        {                                                                     \
            bool active = (base + (K)) < e1;                                  \
            int rel = (int)((RK.x >> 17) & 15u);                              \
            float val = active ? __uint_as_float(RK.y) : 0.f;                 \
            bool chg = (rel != currel) && active;                             \
            float t0 = chg ? 0.f : acc[0];                                    \
            float t1 = chg ? 0.f : acc[1];                                    \
            float t2 = chg ? 0.f : acc[2];                                    \
            float t3 = chg ? 0.f : acc[3];                                    \
            acc[0] = fmaf(val, VK.x, t0);                                     \
            acc[1] = fmaf(val, VK.y, t1);                                     \
            acc[2] = fmaf(val, VK.z, t2);                                     \
            acc[3] = fmaf(val, VK.w, t3);                                     \
            currel = active ? rel : currel;                                   \
            int row = active ? nloc : 32;                                     \
            unsigned off = (unsigned)(rel * 128 + p * 8);                     \
            unsigned addr = (unsigned)row * 2048u                             \
                          + (off ^ ((unsigned)(row & 7) << 4));               \
            unsigned lo, hi;                                                  \
            asm("v_cvt_pk_bf16_f32 %0, %1, %2" : "=v"(lo)                     \
                : "v"(acc[0]), "v"(acc[1]));                                  \
            asm("v_cvt_pk_bf16_f32 %0, %1, %2" : "=v"(hi)                     \
                : "v"(acc[2]), "v"(acc[3]));                                  \
            *(uint2*)(smem + addr) = make_uint2(lo, hi);                      \
        }
        PROC(0, r0, v0) PROC(1, r1, v1) PROC(2, r2, v2) PROC(3, r3, v3)
        PROC(4, r4, v4) PROC(5, r5, v5) PROC(6, r6, v6) PROC(7, r7, v7)
#undef PROC
        r0 = n0; r1 = n1; r2 = n2; r3 = n3;
        r4 = n4; r5 = n5; r6 = n6; r7 = n7;
    }
    __syncthreads();

    /* ---- GEMM: [32 x 1024] @ veff[1024 x 128]; wave w owns h-block w ---- */
    int l15 = lane & 15, lhi = lane >> 4;
    unsigned axor = (unsigned)((l15 & 7) << 4);
    f32x4 acc0 = (f32x4)0.f, acc1 = (f32x4)0.f;
#pragma unroll
    for (int kt = 0; kt < 32; ++kt) {
        short8 b  = ((const short8*)veff)[(size_t)(kt * 8 + w) * 64 + lane];
        unsigned cb = (unsigned)(kt * 64 + lhi * 16);
        short8 a0 = *(const short8*)(smem + (((unsigned)l15 * 2048 + cb) ^ axor));
        short8 a1 = *(const short8*)(smem + (((unsigned)(16 + l15) * 2048 + cb) ^ axor));
        acc0 = __builtin_amdgcn_mfma_f32_16x16x32_bf16(a0, b, acc0, 0, 0, 0);
        acc1 = __builtin_amdgcn_mfma_f32_16x16x32_bf16(a1, b, acc1, 0, 0, 0);
    }
    int h = w * 16 + l15;
    float bv = bias[h];
#pragma unroll
    for (int j = 0; j < 4; ++j) {
        out[(size_t)(g * 32 + lhi * 4 + j) * HDIM + h]      = acc0[j] + bv;
        out[(size_t)(g * 32 + 16 + lhi * 4 + j) * HDIM + h] = acc1[j] + bv;
    }
}

/* ---------- slow fallback (only if ws too small) ---------- */
__global__ __launch_bounds__(256) void build_veff_plain(
        const float* __restrict__ W, const float* __restrict__ Wc,
        float* __restrict__ veff) {
    int idx = blockIdx.x * 256 + threadIdx.x;
    int c = idx >> 7, h = idx & 127;
    float acc = 0.f;
#pragma unroll
    for (int b = 0; b < NBASE; ++b)
        acc += Wc[(c & 15) * NBASE + b] * W[(b * DIM + (c >> 4)) * HDIM + h];
    veff[c * HDIM + h] = acc;
}
__global__ __launch_bounds__(256) void init_out_bias(
        const float* __restrict__ bias, float* __restrict__ out) {
    int idx = blockIdx.x * 256 + threadIdx.x;
    if (idx < N_NODES * HDIM) out[idx] = bias[idx & 127];
}
__global__ __launch_bounds__(128) void edge_slow(
        const float* __restrict__ vertex, const float* __restrict__ eval,
        const int* __restrict__ esrc, const int* __restrict__ edst,
        const int* __restrict__ erel, const float* __restrict__ veff,
        float* __restrict__ out) {
    int e = blockIdx.x;
    int h = threadIdx.x;
    __shared__ float vrow[DIM];
    int src = esrc[e], dst = edst[e], rel = erel[e];
    float val = eval[e];
    if (h < DIM) vrow[h] = vertex[(size_t)src * DIM + h];
    __syncthreads();
    float acc = 0.f;
#pragma unroll 8
    for (int d = 0; d < DIM; ++d)
        acc += vrow[d] * veff[(rel * DIM + d) * HDIM + h];
    atomicAdd(out + (size_t)dst * HDIM + h, val * acc);
}

extern "C" void kernel_launch(void* const* d_in, const int* in_sizes, int n_in,
                              void* d_out, int out_size, void* d_ws, size_t ws_size,
                              hipStream_t stream) {
    const float* vertex   = (const float*)d_in[0];
    const float* edge_val = (const float*)d_in[1];
    const float* W        = (const float*)d_in[2];
    const float* W_comp   = (const float*)d_in[3];
    const float* B        = (const float*)d_in[4];
    const int*   edge_src = (const int*)d_in[5];
    const int*   edge_dst = (const int*)d_in[6];
    const int*   edge_rel = (const int*)d_in[7];
    float* out = (float*)d_out;

    if (ws_size >= WS_NEED) {
        __hip_bfloat16* veff = (__hip_bfloat16*)((char*)d_ws + OFF_VEFF);
        int*   cnt   = (int*)((char*)d_ws + OFF_CNT);
        int*   ofs   = (int*)((char*)d_ws + OFF_OFS);
        int*   cur   = (int*)((char*)d_ws + OFF_CUR);
        int*   bsum  = (int*)((char*)d_ws + OFF_BSUM);
        int*   bscan = (int*)((char*)d_ws + OFF_BSC);
        uint2* recs  = (uint2*)((char*)d_ws + OFF_REC);

        hipMemsetAsync(cnt, 0, NSEG * sizeof(int), stream);
        hipMemsetAsync(recs + NEDGE, 0, REC_PAD * sizeof(uint2), stream);
        build_veff_frag<<<KDIM * HDIM / 256, 256, 0, stream>>>(W, W_comp, veff);
        hist_kernel<<<NEDGE / 256, 256, 0, stream>>>(edge_dst, edge_rel, cnt);
        scanA<<<NBLKA, 256, 0, stream>>>(cnt, bsum);
        scanB<<<1, 256, 0, stream>>>(bsum, bscan);
        scanC<<<NBLKA, 256, 0, stream>>>(cnt, bscan, ofs, cur);
        scatter_bin<<<NEDGE / 256, 256, 0, stream>>>(
            edge_src, edge_dst, edge_rel, edge_val, cur, recs);
        fused_agg_gemm<<<N_NODES / 32, 512, 0, stream>>>(vertex, recs, ofs, veff, B, out);
    } else {
        float* veff = (float*)d_ws;
        build_veff_plain<<<KDIM * HDIM / 256, 256, 0, stream>>>(W, W_comp, veff);
        init_out_bias<<<(N_NODES * HDIM + 255) / 256, 256, 0, stream>>>(B, out);
        edge_slow<<<NEDGE, 128, 0, stream>>>(
            vertex, edge_val, edge_src, edge_dst, edge_rel, veff, out);
    }
}

// Round 5
// 224.558 us; speedup vs baseline: 7.0867x; 2.3182x over previous
//
#include <hip/hip_runtime.h>
#include <hip/hip_bf16.h>
#include <stdint.h>

#define N_NODES 100000
#define DIM     64
#define NRELS   16
#define NBASE   8
#define HDIM    128
#define NEDGE   3200000
#define KDIM    1024               /* NRELS*DIM */
#define NSEG    (N_NODES * NRELS)  /* 1,600,000 */

#define CBSH    8                  /* 256 nodes per coarse bucket */
#define CBN     256
#define NCB     391                /* ceil(100000/256) */
#define SEGPB   (CBN * NRELS)      /* 4096 fine segments per bucket */
#define REC_PAD 256

#define P1_BLOCKS 250
#define P1_EPT    50               /* 250*256*50 = 3.2M */
#define HC_BLOCKS 625
#define HC_EPT    20               /* 625*256*20 = 3.2M */

typedef __attribute__((ext_vector_type(8))) short  short8;
typedef __attribute__((ext_vector_type(4))) float  f32x4;

/* ---- ws layout (bytes) ---- */
#define OFF_VEFF  0u
#define OFF_VTXB  262144u                         /* N*DIM*2 = 12,800,000  */
#define OFF_CCNT  13062144u                       /* NCB ints (pad 2048)   */
#define OFF_COFS  13064192u                       /* NCB+1 ints (pad 2048) */
#define OFF_CCUR  13066240u                       /* NCB ints (pad 2048)   */
#define OFF_NOFS  13068288u                       /* (N+1) ints (pad)      */
#define OFF_REC1  13468928u                       /* E * 8                 */
#define OFF_REC2  39068928u                       /* (E+pad) * 8           */
#define WS_NEED   (39068928u + (size_t)(NEDGE + REC_PAD) * 8u)

static __device__ __forceinline__ unsigned short f2bf(float x) {
    union { float f; unsigned u; } t; t.f = x;
    unsigned u = t.u;
    unsigned r = u + 0x7FFFu + ((u >> 16) & 1u);   /* RNE */
    return (unsigned short)(r >> 16);
}

/* ---- kernel 1: Veff in MFMA B-fragment layout (verified r1-r4) ---- */
__global__ __launch_bounds__(256) void build_veff_frag(
        const float* __restrict__ W, const float* __restrict__ Wc,
        __hip_bfloat16* __restrict__ veff) {
    int idx = blockIdx.x * 256 + threadIdx.x;
    int c = idx >> 7;
    int h = idx & 127;
    float acc = 0.f;
#pragma unroll
    for (int b = 0; b < NBASE; ++b)
        acc += Wc[(c & 15) * NBASE + b] * W[(b * DIM + (c >> 4)) * HDIM + h];
    int kt = c >> 5, ko = c & 31;
    int lane = ((ko >> 3) << 4) | (h & 15);
    int j = ko & 7;
    int hb = h >> 4;
    ((unsigned short*)veff)[(size_t)((kt * 8 + hb) * 64 + lane) * 8 + j] = f2bf(acc);
}

/* ---- kernel 2: vertex fp32 -> bf16 (halves gather traffic) ---- */
__global__ __launch_bounds__(256) void vert_to_bf16(
        const float* __restrict__ v, unsigned* __restrict__ vb) {
    int i = blockIdx.x * 256 + threadIdx.x;        /* N*DIM/2 pairs, grid exact */
    float2 f = ((const float2*)v)[i];
    unsigned r;
    asm("v_cvt_pk_bf16_f32 %0, %1, %2" : "=v"(r) : "v"(f.x), "v"(f.y));
    vb[i] = r;
}

/* ---- kernel 3: coarse histogram (LDS-aggregated) ---- */
__global__ __launch_bounds__(256) void hist_coarse(
        const int* __restrict__ edst, int* __restrict__ ccnt) {
    __shared__ int l[NCB];
    int t = threadIdx.x;
    for (int i = t; i < NCB; i += 256) l[i] = 0;
    __syncthreads();
    int base = blockIdx.x * (256 * HC_EPT);
#pragma unroll
    for (int k = 0; k < HC_EPT; ++k)
        atomicAdd(&l[edst[base + k * 256 + t] >> CBSH], 1);
    __syncthreads();
    for (int i = t; i < NCB; i += 256)
        if (l[i]) atomicAdd(&ccnt[i], l[i]);
}

/* ---- kernel 4: scan of 391 bucket counts (1 block) ---- */
__global__ __launch_bounds__(256) void scan_coarse(
        const int* __restrict__ ccnt, int* __restrict__ cofs,
        int* __restrict__ ccur, int* __restrict__ nofs) {
    int t = threadIdx.x;
    int lane = t & 63, w = t >> 6;
    int i0 = 2 * t, i1 = 2 * t + 1;
    int v0 = (i0 < NCB) ? ccnt[i0] : 0;
    int v1 = (i1 < NCB) ? ccnt[i1] : 0;
    int s = v0 + v1;
    int x = s;
#pragma unroll
    for (int d = 1; d < 64; d <<= 1) { int y = __shfl_up(x, d); if (lane >= d) x += y; }
    __shared__ int wsum[4];
    if (lane == 63) wsum[w] = x;
    __syncthreads();
    int wadd = 0;
    for (int i = 0; i < w; ++i) wadd += wsum[i];
    int run = wadd + x - s;                         /* exclusive */
    if (i0 < NCB) { cofs[i0] = run; ccur[i0] = run; }
    run += v0;
    if (i0 == NCB - 1) { cofs[NCB] = run; nofs[N_NODES] = run; }
    if (i1 < NCB) { cofs[i1] = run; ccur[i1] = run; }
    run += v1;
    if (i1 == NCB - 1) { cofs[NCB] = run; nofs[N_NODES] = run; }
}

/* ---- kernel 5: pass-1 coarse scatter (block counting sort) ----
   Writes land in ~260B contiguous per-bucket runs -> ~1.25x inflation. */
__global__ __launch_bounds__(256) void pass1_scatter(
        const int* __restrict__ esrc, const int* __restrict__ edst,
        const int* __restrict__ erel, const float* __restrict__ eval,
        int* __restrict__ ccur, uint2* __restrict__ recs1) {
    __shared__ int lcnt[NCB], lbase[NCB], lpos[NCB];
    int t = threadIdx.x;
    int base = blockIdx.x * (256 * P1_EPT);
    for (int i = t; i < NCB; i += 256) { lcnt[i] = 0; lpos[i] = 0; }
    __syncthreads();
    /* phase A: local histogram */
    for (int k = 0; k < P1_EPT; ++k)
        atomicAdd(&lcnt[edst[base + k * 256 + t] >> CBSH], 1);
    __syncthreads();
    /* phase B: reserve global runs */
    for (int i = t; i < NCB; i += 256)
        if (lcnt[i] > 0) lbase[i] = atomicAdd(&ccur[i], lcnt[i]);
    __syncthreads();
    /* phase C: scatter into runs */
    for (int k = 0; k < P1_EPT; ++k) {
        int e = base + k * 256 + t;
        int dst = edst[e];
        int cb = dst >> CBSH;
        int slot = atomicAdd(&lpos[cb], 1);
        uint2 r;
        r.x = (unsigned)esrc[e] | ((unsigned)erel[e] << 17)
            | ((unsigned)(dst & (CBN - 1)) << 21);
        r.y = __float_as_uint(eval[e]);
        recs1[lbase[cb] + slot] = r;
    }
}

/* ---- kernel 6: pass-2 fine scatter within L2-resident bucket window ----
   Also produces nofs[] (per-node record offsets) from the LDS scan,
   replacing the old global fine hist + 3-kernel scan. */
__global__ __launch_bounds__(256) void pass2_scatter(
        const uint2* __restrict__ recs1, const int* __restrict__ cofs,
        int* __restrict__ nofs, uint2* __restrict__ recs2) {
    __shared__ int cur[SEGPB];
    __shared__ int wsum[4];
    int t = threadIdx.x;
    int cb = blockIdx.x;
    int r0 = cofs[cb], r1 = cofs[cb + 1];
    for (int i = t; i < SEGPB; i += 256) cur[i] = 0;
    __syncthreads();
    /* local fine histogram over 4096 segments */
    for (int i = r0 + t; i < r1; i += 256) {
        unsigned rx = recs1[i].x;
        int lseg = (int)(((rx >> 21) & 255u) * 16u + ((rx >> 17) & 15u));
        atomicAdd(&cur[lseg], 1);
    }
    __syncthreads();
    /* exclusive scan: each thread owns cur[t*16 .. t*16+15] */
    int b0 = t * 16;
    int vals[16]; int tsum = 0;
#pragma unroll
    for (int k = 0; k < 16; ++k) { vals[k] = cur[b0 + k]; tsum += vals[k]; }
    int lane = t & 63, w = t >> 6;
    int x = tsum;
#pragma unroll
    for (int d = 1; d < 64; d <<= 1) { int y = __shfl_up(x, d); if (lane >= d) x += y; }
    if (lane == 63) wsum[w] = x;
    __syncthreads();
    int wadd = 0;
    for (int i = 0; i < w; ++i) wadd += wsum[i];
    int run = r0 + wadd + x - tsum;                 /* global exclusive base */
    int node = cb * CBN + t;                        /* seg t*16 = node boundary */
    if (node < N_NODES) nofs[node] = run;
#pragma unroll
    for (int k = 0; k < 16; ++k) { cur[b0 + k] = run; run += vals[k]; }
    __syncthreads();
    /* scatter within window (L2-resident) */
    for (int i = r0 + t; i < r1; i += 256) {
        uint2 r = recs1[i];
        int lseg = (int)(((r.x >> 21) & 255u) * 16u + ((r.x >> 17) & 15u));
        int pos = atomicAdd(&cur[lseg], 1);
        recs2[pos] = r;
    }
}

/* ---- kernel 7: fused branchless aggregate + MFMA GEMM (r4 structure,
   bf16 vertex gathers: 128B/edge) ---- */
__global__ __launch_bounds__(512, 4) void fused_agg_gemm(
        const uint2* __restrict__ vtxb, const uint2* __restrict__ recs,
        const int* __restrict__ nofs, const __hip_bfloat16* __restrict__ veff,
        const float* __restrict__ bias, float* __restrict__ out) {
    __shared__ __align__(16) unsigned char smem[33 * 2048];   /* 32 A-rows + scratch */
    int t = threadIdx.x;
    int g = blockIdx.x;
    int w = t >> 6, lane = t & 63;
    int q = lane >> 4, p = lane & 15;
    int nloc = w * 4 + q;
    int n = g * 32 + nloc;

    for (int i = t; i < 33 * 2048 / 16; i += 512)
        ((uint4*)smem)[i] = make_uint4(0, 0, 0, 0);
    __syncthreads();

    int e0 = nofs[n];
    int e1 = nofs[n + 1];

    f32x4 acc = (f32x4)0.f;
    int currel = -1;

    uint2 r0, r1, r2, r3, r4, r5, r6, r7;
    r0 = recs[e0 + 0]; r1 = recs[e0 + 1]; r2 = recs[e0 + 2]; r3 = recs[e0 + 3];
    r4 = recs[e0 + 4]; r5 = recs[e0 + 5]; r6 = recs[e0 + 6]; r7 = recs[e0 + 7];

    for (int base = e0; __any(base < e1); base += 8) {
        uint2 v0 = vtxb[(size_t)(r0.x & 0x1FFFFu) * 16 + p];
        uint2 v1 = vtxb[(size_t)(r1.x & 0x1FFFFu) * 16 + p];
        uint2 v2 = vtxb[(size_t)(r2.x & 0x1FFFFu) * 16 + p];
        uint2 v3 = vtxb[(size_t)(r3.x & 0x1FFFFu) * 16 + p];
        uint2 v4 = vtxb[(size_t)(r4.x & 0x1FFFFu) * 16 + p];
        uint2 v5 = vtxb[(size_t)(r5.x & 0x1FFFFu) * 16 + p];
        uint2 v6 = vtxb[(size_t)(r6.x & 0x1FFFFu) * 16 + p];
        uint2 v7 = vtxb[(size_t)(r7.x & 0x1FFFFu) * 16 + p];
        int nb = base + 8;
        uint2 n0 = recs[nb + 0], n1 = recs[nb + 1], n2 = recs[nb + 2], n3 = recs[nb + 3];
        uint2 n4 = recs[nb + 4], n5 = recs[nb + 5], n6 = recs[nb + 6], n7 = recs[nb + 7];

#define PROC(K, RK, VK)                                                       \
        {                                                                     \
            bool active = (base + (K)) < e1;                                  \
            int rel = (int)((RK.x >> 17) & 15u);                              \
            float val = active ? __uint_as_float(RK.y) : 0.f;                 \
            bool chg = (rel != currel) && active;                             \
            float f0 = __uint_as_float(VK.x << 16);                           \
            float f1 = __uint_as_float(VK.x & 0xFFFF0000u);                   \
            float f2 = __uint_as_float(VK.y << 16);                           \
            float f3 = __uint_as_float(VK.y & 0xFFFF0000u);                   \
            float t0 = chg ? 0.f : acc[0];                                    \
            float t1 = chg ? 0.f : acc[1];                                    \
            float t2 = chg ? 0.f : acc[2];                                    \
            float t3 = chg ? 0.f : acc[3];                                    \
            acc[0] = fmaf(val, f0, t0);                                       \
            acc[1] = fmaf(val, f1, t1);                                       \
            acc[2] = fmaf(val, f2, t2);                                       \
            acc[3] = fmaf(val, f3, t3);                                       \
            currel = active ? rel : currel;                                   \
            int row = active ? nloc : 32;                                     \
            unsigned off = (unsigned)(rel * 128 + p * 8);                     \
            unsigned addr = (unsigned)row * 2048u                             \
                          + (off ^ ((unsigned)(row & 7) << 4));               \
            unsigned lo, hi;                                                  \
            asm("v_cvt_pk_bf16_f32 %0, %1, %2" : "=v"(lo)                     \
                : "v"(acc[0]), "v"(acc[1]));                                  \
            asm("v_cvt_pk_bf16_f32 %0, %1, %2" : "=v"(hi)                     \
                : "v"(acc[2]), "v"(acc[3]));                                  \
            *(uint2*)(smem + addr) = make_uint2(lo, hi);                      \
        }
        PROC(0, r0, v0) PROC(1, r1, v1) PROC(2, r2, v2) PROC(3, r3, v3)
        PROC(4, r4, v4) PROC(5, r5, v5) PROC(6, r6, v6) PROC(7, r7, v7)
#undef PROC
        r0 = n0; r1 = n1; r2 = n2; r3 = n3;
        r4 = n4; r5 = n5; r6 = n6; r7 = n7;
    }
    __syncthreads();

    /* ---- GEMM: [32 x 1024] @ veff[1024 x 128]; wave w owns h-block w ---- */
    int l15 = lane & 15, lhi = lane >> 4;
    unsigned axor = (unsigned)((l15 & 7) << 4);
    f32x4 acc0 = (f32x4)0.f, acc1 = (f32x4)0.f;
#pragma unroll
    for (int kt = 0; kt < 32; ++kt) {
        short8 b  = ((const short8*)veff)[(size_t)(kt * 8 + w) * 64 + lane];
        unsigned cb = (unsigned)(kt * 64 + lhi * 16);
        short8 a0 = *(const short8*)(smem + (((unsigned)l15 * 2048 + cb) ^ axor));
        short8 a1 = *(const short8*)(smem + (((unsigned)(16 + l15) * 2048 + cb) ^ axor));
        acc0 = __builtin_amdgcn_mfma_f32_16x16x32_bf16(a0, b, acc0, 0, 0, 0);
        acc1 = __builtin_amdgcn_mfma_f32_16x16x32_bf16(a1, b, acc1, 0, 0, 0);
    }
    int h = w * 16 + l15;
    float bv = bias[h];
#pragma unroll
    for (int j = 0; j < 4; ++j) {
        out[(size_t)(g * 32 + lhi * 4 + j) * HDIM + h]      = acc0[j] + bv;
        out[(size_t)(g * 32 + 16 + lhi * 4 + j) * HDIM + h] = acc1[j] + bv;
    }
}

/* ---------- slow fallback (only if ws too small) ---------- */
__global__ __launch_bounds__(256) void build_veff_plain(
        const float* __restrict__ W, const float* __restrict__ Wc,
        float* __restrict__ veff) {
    int idx = blockIdx.x * 256 + threadIdx.x;
    int c = idx >> 7, h = idx & 127;
    float acc = 0.f;
#pragma unroll
    for (int b = 0; b < NBASE; ++b)
        acc += Wc[(c & 15) * NBASE + b] * W[(b * DIM + (c >> 4)) * HDIM + h];
    veff[c * HDIM + h] = acc;
}
__global__ __launch_bounds__(256) void init_out_bias(
        const float* __restrict__ bias, float* __restrict__ out) {
    int idx = blockIdx.x * 256 + threadIdx.x;
    if (idx < N_NODES * HDIM) out[idx] = bias[idx & 127];
}
__global__ __launch_bounds__(128) void edge_slow(
        const float* __restrict__ vertex, const float* __restrict__ eval,
        const int* __restrict__ esrc, const int* __restrict__ edst,
        const int* __restrict__ erel, const float* __restrict__ veff,
        float* __restrict__ out) {
    int e = blockIdx.x;
    int h = threadIdx.x;
    __shared__ float vrow[DIM];
    int src = esrc[e], dst = edst[e], rel = erel[e];
    float val = eval[e];
    if (h < DIM) vrow[h] = vertex[(size_t)src * DIM + h];
    __syncthreads();
    float acc = 0.f;
#pragma unroll 8
    for (int d = 0; d < DIM; ++d)
        acc += vrow[d] * veff[(rel * DIM + d) * HDIM + h];
    atomicAdd(out + (size_t)dst * HDIM + h, val * acc);
}

extern "C" void kernel_launch(void* const* d_in, const int* in_sizes, int n_in,
                              void* d_out, int out_size, void* d_ws, size_t ws_size,
                              hipStream_t stream) {
    const float* vertex   = (const float*)d_in[0];
    const float* edge_val = (const float*)d_in[1];
    const float* W        = (const float*)d_in[2];
    const float* W_comp   = (const float*)d_in[3];
    const float* B        = (const float*)d_in[4];
    const int*   edge_src = (const int*)d_in[5];
    const int*   edge_dst = (const int*)d_in[6];
    const int*   edge_rel = (const int*)d_in[7];
    float* out = (float*)d_out;

    if (ws_size >= WS_NEED) {
        __hip_bfloat16* veff = (__hip_bfloat16*)((char*)d_ws + OFF_VEFF);
        unsigned* vtxb = (unsigned*)((char*)d_ws + OFF_VTXB);
        int*   ccnt  = (int*)((char*)d_ws + OFF_CCNT);
        int*   cofs  = (int*)((char*)d_ws + OFF_COFS);
        int*   ccur  = (int*)((char*)d_ws + OFF_CCUR);
        int*   nofs  = (int*)((char*)d_ws + OFF_NOFS);
        uint2* recs1 = (uint2*)((char*)d_ws + OFF_REC1);
        uint2* recs2 = (uint2*)((char*)d_ws + OFF_REC2);

        hipMemsetAsync(ccnt, 0, NCB * sizeof(int), stream);
        hipMemsetAsync(recs2 + NEDGE, 0, REC_PAD * sizeof(uint2), stream);
        build_veff_frag<<<KDIM * HDIM / 256, 256, 0, stream>>>(W, W_comp, veff);
        vert_to_bf16<<<N_NODES * DIM / 2 / 256, 256, 0, stream>>>(vertex, vtxb);
        hist_coarse<<<HC_BLOCKS, 256, 0, stream>>>(edge_dst, ccnt);
        scan_coarse<<<1, 256, 0, stream>>>(ccnt, cofs, ccur, nofs);
        pass1_scatter<<<P1_BLOCKS, 256, 0, stream>>>(
            edge_src, edge_dst, edge_rel, edge_val, ccur, recs1);
        pass2_scatter<<<NCB, 256, 0, stream>>>(recs1, cofs, nofs, recs2);
        fused_agg_gemm<<<N_NODES / 32, 512, 0, stream>>>(
            (const uint2*)vtxb, recs2, nofs, veff, B, out);
    } else {
        float* veff = (float*)d_ws;
        build_veff_plain<<<KDIM * HDIM / 256, 256, 0, stream>>>(W, W_comp, veff);
        init_out_bias<<<(N_NODES * HDIM + 255) / 256, 256, 0, stream>>>(B, out);
        edge_slow<<<NEDGE, 128, 0, stream>>>(
            vertex, edge_val, edge_src, edge_dst, edge_rel, veff, out);
    }
}